// Round 5
// baseline (930.591 us; speedup 1.0000x reference)
//
#include <hip/hip_runtime.h>
#include <hip/hip_cooperative_groups.h>
#include <hip/hip_bf16.h>

#define NE 50000
#define NA 800000
#define NC 100000

namespace cg = cooperative_groups;

typedef _Float16 f16;
typedef f16 half8 __attribute__((ext_vector_type(8)));
typedef f16 f16x2 __attribute__((ext_vector_type(2)));
typedef float f32x4 __attribute__((ext_vector_type(4)));

// f16-element offsets inside the converted-weight arena
#define OFF_ENC1 0
#define OFF_ENC2 8192
#define OFF_MSGPQ 24576    // 3 layers x 32768 (P block 16384 + Q block 16384)
#define OFF_UPD1 122880    // 3 layers x 32768, fused layout [n][256]
#define OFF_UPD2 221184    // 3 layers x 16384
#define OFF_PREDPQ 270336  // 32768
#define OFF_PREDW2 303104  // 16384
#define TOTAL_WT 319488

#define R_FUSE 49536       // 3*129 groups x 128 threads
#define R_WT 270336
#define R_X 800000         // NE*64/4
#define R_Z 50000
#define PTOT (R_FUSE + R_WT + R_X + R_Z)

struct KP {
    const float* edge_features;
    const int *adj_dst, *adj_src, *cand_i, *cand_j;
    const float *enc_b1, *enc_b2;
    const float *msg_b1, *msg_W2, *msg_b2;
    const float *upd_W1, *upd_b1, *upd_b2;
    const float *pred_b1, *pred_b2, *pred_W3, *pred_b3;
    f16* wt;
    float* fbias;
    f16 *xb, *eA, *eB, *P0, *Q0, *P1, *Q1;
    int *segStart, *segEnd;
    float *outP, *outL;
    const float* wsrc[20];
    int wK[20], wOff[20], wStr[20], wCum[21];
};

// ---------------- shared device bodies ----------------

__device__ __forceinline__ void prep_item(const KP& p, int gid) {
    if (gid < R_FUSE) {
        // fused W2U = msg_W2 @ upd_W1[128:256] and fbias; coalesced per 128-group
        int g = gid >> 7, n = gid & 127;
        int l = g / 129, kk = g % 129;
        const float* U1b = p.upd_W1 + (size_t)l * 32768 + 16384;
        if (kk < 128) {
            const float* w2row = p.msg_W2 + (size_t)l * 16384 + (size_t)kk * 128;
            float s = 0.f;
            for (int m = 0; m < 128; ++m) s += w2row[m] * U1b[m * 128 + n];
            p.wt[OFF_UPD1 + l * 32768 + n * 256 + 128 + kk] = (f16)s;
        } else {
            const float* b2 = p.msg_b2 + l * 128;
            float s = p.upd_b1[l * 128 + n];
            for (int m = 0; m < 128; ++m) s += b2[m] * U1b[m * 128 + n];
            p.fbias[l * 128 + n] = s;
        }
    } else if (gid < R_FUSE + R_WT) {
        int e = gid - R_FUSE;
        int j = 0;
#pragma unroll
        for (int i = 1; i < 20; ++i) j += (e >= p.wCum[i]) ? 1 : 0;
        int r = e - p.wCum[j];
        int K = p.wK[j];
        int k = r % K, n = r / K;
        p.wt[p.wOff[j] + n * p.wStr[j] + k] = (f16)p.wsrc[j][(size_t)k * 128 + n];
    } else if (gid < R_FUSE + R_WT + R_X) {
        int g2 = gid - (R_FUSE + R_WT);
        float4 v = ((const float4*)p.edge_features)[g2];
        f16x2 a = {(f16)v.x, (f16)v.y}, b = {(f16)v.z, (f16)v.w};
        ((f16x2*)p.xb)[g2 * 2] = a;
        ((f16x2*)p.xb)[g2 * 2 + 1] = b;
    } else if (gid < PTOT) {
        int z = gid - (R_FUSE + R_WT + R_X);
        p.segStart[z] = 0;
        p.segEnd[z] = 0;
    }
}

__device__ __forceinline__ void degseg_item(const KP& p, int i) {
    int d = p.adj_dst[i];
    if (i == 0 || p.adj_dst[i - 1] != d) p.segStart[d] = i;
    if (i == NA - 1 || p.adj_dst[i + 1] != d) p.segEnd[d] = i + 1;
}

// one 64-row tile: [agg into A-right]? -> GEMM1(K1) -> relu -> GEMM2 -> e' -> P/Q GEMMs
template <int K1, bool AGG>
__device__ __forceinline__ void do_tile(
    char* SMEM, int tile, const f16* __restrict__ in0,
    const f16* __restrict__ Pin, const f16* __restrict__ Qin,
    const int* __restrict__ adj_src, const int* __restrict__ segStart,
    const int* __restrict__ segEnd,
    const f16* __restrict__ w1t, const int w1s, const float* __restrict__ b1v,
    const f16* __restrict__ w2t, const float* __restrict__ b2v, const bool reluOut,
    f16* __restrict__ oute,
    const f16* __restrict__ wpq, const float* __restrict__ bPp,
    f16* __restrict__ Pout, f16* __restrict__ Qout) {
    constexpr int SA = K1 + 8;   // f16 stride
    constexpr int SH = 136;      // f16 stride for H/E
    f16* Abuf = (f16*)SMEM;
    f16* Hbuf = (f16*)SMEM;                  // aliases Abuf low (dead after GEMM1)
    f16* Ebuf = (f16*)(SMEM + 17408);        // disjoint from Hbuf
    const int t = threadIdx.x, lane = t & 63, wave = t >> 6;
    const int quad = lane >> 4, mn = lane & 15, n0 = wave * 32;
    const int rbase = tile << 6;

    // ---- stage A-tile (left half from global; right half from in-wave agg)
    if constexpr (K1 == 64) {
#pragma unroll
        for (int it = 0; it < 2; ++it) {
            int u = it * 256 + t, row = u >> 3, k = (u & 7) * 8, gr = rbase + row;
            half8 v = {};
            if (gr < NE) v = *(const half8*)(in0 + (size_t)gr * 64 + k);
            *(half8*)(Abuf + row * SA + k) = v;
        }
    } else {
#pragma unroll
        for (int it = 0; it < 4; ++it) {
            int u = it * 256 + t, row = u >> 4, k = (u & 15) * 8, gr = rbase + row;
            half8 v = {};
            if (gr < NE) v = *(const half8*)(in0 + (size_t)gr * 128 + k);
            *(half8*)(Abuf + row * SA + k) = v;
        }
    }
    if constexpr (AGG) {
        // wave computes hbar for its 16 rows: inv_deg * sum relu(P[dst]+Q[src])
        for (int i = 0; i < 16; ++i) {
            int dst = rbase + wave * 16 + i;
            float a0 = 0.f, a1 = 0.f;
            if (dst < NE) {
                f16x2 p2 = ((const f16x2*)Pin)[(size_t)dst * 64 + lane];
                float pp0 = (float)p2.x, pp1 = (float)p2.y;
                int s = segStart[dst];
                int deg = segEnd[dst] - s;
                if (deg == 0) {
                    f16x2 q2 = ((const f16x2*)Qin)[(size_t)dst * 64 + lane];
                    a0 = fmaxf(pp0 + (float)q2.x, 0.f);
                    a1 = fmaxf(pp1 + (float)q2.y, 0.f);
                } else {
                    float x0 = 0.f, x1 = 0.f;
                    int j = 0;
                    for (; j + 7 < deg; j += 8) {
                        f16x2 q[8];
#pragma unroll
                        for (int u2 = 0; u2 < 8; ++u2)
                            q[u2] = ((const f16x2*)Qin)[(size_t)adj_src[s + j + u2] * 64 + lane];
#pragma unroll
                        for (int u2 = 0; u2 < 8; ++u2) {
                            x0 += fmaxf(pp0 + (float)q[u2].x, 0.f);
                            x1 += fmaxf(pp1 + (float)q[u2].y, 0.f);
                        }
                    }
                    for (; j < deg; ++j) {
                        f16x2 q2 = ((const f16x2*)Qin)[(size_t)adj_src[s + j] * 64 + lane];
                        x0 += fmaxf(pp0 + (float)q2.x, 0.f);
                        x1 += fmaxf(pp1 + (float)q2.y, 0.f);
                    }
                    float sc = 1.f / (float)deg;
                    a0 = x0 * sc;
                    a1 = x1 * sc;
                }
            }
            f16x2 o = {(f16)a0, (f16)a1};
            *(f16x2*)(Abuf + (wave * 16 + i) * SA + 128 + lane * 2) = o;
        }
    }
    __syncthreads();

    // ---- GEMM1: [64 x K1] @ [K1 x 128] + b1, relu -> Hbuf
    f32x4 acc[4][2];
    {
        float bb0 = b1v[n0 + mn], bb1 = b1v[n0 + 16 + mn];
#pragma unroll
        for (int mt = 0; mt < 4; ++mt) {
            acc[mt][0] = (f32x4){bb0, bb0, bb0, bb0};
            acc[mt][1] = (f32x4){bb1, bb1, bb1, bb1};
        }
    }
#pragma unroll
    for (int kc = 0; kc < K1 / 32; ++kc) {
        half8 wA = *(const half8*)(w1t + (size_t)(n0 + mn) * w1s + kc * 32 + quad * 8);
        half8 wB = *(const half8*)(w1t + (size_t)(n0 + 16 + mn) * w1s + kc * 32 + quad * 8);
        half8 af[4];
#pragma unroll
        for (int mt = 0; mt < 4; ++mt)
            af[mt] = *(const half8*)(Abuf + (mt * 16 + mn) * SA + kc * 32 + quad * 8);
#pragma unroll
        for (int mt = 0; mt < 4; ++mt) {
            acc[mt][0] = __builtin_amdgcn_mfma_f32_16x16x32_f16(af[mt], wA, acc[mt][0], 0, 0, 0);
            acc[mt][1] = __builtin_amdgcn_mfma_f32_16x16x32_f16(af[mt], wB, acc[mt][1], 0, 0, 0);
        }
    }
    __syncthreads();  // A reads done before aliased Hbuf writes
#pragma unroll
    for (int mt = 0; mt < 4; ++mt)
#pragma unroll
        for (int nt = 0; nt < 2; ++nt)
#pragma unroll
            for (int r = 0; r < 4; ++r)
                Hbuf[(mt * 16 + quad * 4 + r) * SH + n0 + nt * 16 + mn] =
                    (f16)fmaxf(acc[mt][nt][r], 0.f);
    __syncthreads();

    // ---- GEMM2: [64x128]@[128x128] + b2 (+relu) -> Ebuf
    {
        float bb0 = b2v[n0 + mn], bb1 = b2v[n0 + 16 + mn];
#pragma unroll
        for (int mt = 0; mt < 4; ++mt) {
            acc[mt][0] = (f32x4){bb0, bb0, bb0, bb0};
            acc[mt][1] = (f32x4){bb1, bb1, bb1, bb1};
        }
    }
#pragma unroll
    for (int kc = 0; kc < 4; ++kc) {
        half8 wA = *(const half8*)(w2t + (size_t)(n0 + mn) * 128 + kc * 32 + quad * 8);
        half8 wB = *(const half8*)(w2t + (size_t)(n0 + 16 + mn) * 128 + kc * 32 + quad * 8);
        half8 af[4];
#pragma unroll
        for (int mt = 0; mt < 4; ++mt)
            af[mt] = *(const half8*)(Hbuf + (mt * 16 + mn) * SH + kc * 32 + quad * 8);
#pragma unroll
        for (int mt = 0; mt < 4; ++mt) {
            acc[mt][0] = __builtin_amdgcn_mfma_f32_16x16x32_f16(af[mt], wA, acc[mt][0], 0, 0, 0);
            acc[mt][1] = __builtin_amdgcn_mfma_f32_16x16x32_f16(af[mt], wB, acc[mt][1], 0, 0, 0);
        }
    }
#pragma unroll
    for (int mt = 0; mt < 4; ++mt)
#pragma unroll
        for (int nt = 0; nt < 2; ++nt)
#pragma unroll
            for (int r = 0; r < 4; ++r) {
                float v = acc[mt][nt][r];
                if (reluOut) v = fmaxf(v, 0.f);
                Ebuf[(mt * 16 + quad * 4 + r) * SH + n0 + nt * 16 + mn] = (f16)v;
            }
    __syncthreads();  // Ebuf ready

    // ---- vectorized e' store from Ebuf
#pragma unroll
    for (int it = 0; it < 4; ++it) {
        int u = it * 256 + t, row = u >> 4, k = (u & 15) * 8, gr = rbase + row;
        if (gr < NE) {
            half8 v = *(const half8*)(Ebuf + row * SH + k);
            *(half8*)(oute + (size_t)gr * 128 + k) = v;
        }
    }

    // ---- P GEMM (bias) then Q GEMM (no bias) on e'
    {
        float bb0 = bPp[n0 + mn], bb1 = bPp[n0 + 16 + mn];
#pragma unroll
        for (int mt = 0; mt < 4; ++mt) {
            acc[mt][0] = (f32x4){bb0, bb0, bb0, bb0};
            acc[mt][1] = (f32x4){bb1, bb1, bb1, bb1};
        }
    }
#pragma unroll
    for (int kc = 0; kc < 4; ++kc) {
        half8 wA = *(const half8*)(wpq + (size_t)(n0 + mn) * 128 + kc * 32 + quad * 8);
        half8 wB = *(const half8*)(wpq + (size_t)(n0 + 16 + mn) * 128 + kc * 32 + quad * 8);
        half8 af[4];
#pragma unroll
        for (int mt = 0; mt < 4; ++mt)
            af[mt] = *(const half8*)(Ebuf + (mt * 16 + mn) * SH + kc * 32 + quad * 8);
#pragma unroll
        for (int mt = 0; mt < 4; ++mt) {
            acc[mt][0] = __builtin_amdgcn_mfma_f32_16x16x32_f16(af[mt], wA, acc[mt][0], 0, 0, 0);
            acc[mt][1] = __builtin_amdgcn_mfma_f32_16x16x32_f16(af[mt], wB, acc[mt][1], 0, 0, 0);
        }
    }
#pragma unroll
    for (int mt = 0; mt < 4; ++mt)
#pragma unroll
        for (int nt = 0; nt < 2; ++nt)
#pragma unroll
            for (int r = 0; r < 4; ++r) {
                int gr = rbase + mt * 16 + quad * 4 + r;
                if (gr < NE)
                    Pout[(size_t)gr * 128 + n0 + nt * 16 + mn] = (f16)acc[mt][nt][r];
            }
#pragma unroll
    for (int mt = 0; mt < 4; ++mt) {
        acc[mt][0] = (f32x4){0.f, 0.f, 0.f, 0.f};
        acc[mt][1] = (f32x4){0.f, 0.f, 0.f, 0.f};
    }
#pragma unroll
    for (int kc = 0; kc < 4; ++kc) {
        half8 wA = *(const half8*)(wpq + 16384 + (size_t)(n0 + mn) * 128 + kc * 32 + quad * 8);
        half8 wB = *(const half8*)(wpq + 16384 + (size_t)(n0 + 16 + mn) * 128 + kc * 32 + quad * 8);
        half8 af[4];
#pragma unroll
        for (int mt = 0; mt < 4; ++mt)
            af[mt] = *(const half8*)(Ebuf + (mt * 16 + mn) * SH + kc * 32 + quad * 8);
#pragma unroll
        for (int mt = 0; mt < 4; ++mt) {
            acc[mt][0] = __builtin_amdgcn_mfma_f32_16x16x32_f16(af[mt], wA, acc[mt][0], 0, 0, 0);
            acc[mt][1] = __builtin_amdgcn_mfma_f32_16x16x32_f16(af[mt], wB, acc[mt][1], 0, 0, 0);
        }
    }
#pragma unroll
    for (int mt = 0; mt < 4; ++mt)
#pragma unroll
        for (int nt = 0; nt < 2; ++nt)
#pragma unroll
            for (int r = 0; r < 4; ++r) {
                int gr = rbase + mt * 16 + quad * 4 + r;
                if (gr < NE)
                    Qout[(size_t)gr * 128 + n0 + nt * 16 + mn] = (f16)acc[mt][nt][r];
            }
    __syncthreads();  // protect LDS before next tile
}

// one predictor tile: h1=relu(P1[i]+Q1[j]); h2=relu(h1@W2+b2); logit=h2@w3+b3; sigmoid
__device__ __forceinline__ void pred_tile(const KP& p, char* SMEM, float* w3s,
                                          float* psum, int tile, float b3v) {
    constexpr int SA = 136, SO = 133;
    f16* Abuf = (f16*)SMEM;
    float* Obuf = (float*)SMEM;
    const int t = threadIdx.x, lane = t & 63, wave = t >> 6;
    const int quad = lane >> 4, mn = lane & 15, n0 = wave * 32;
    const int rbase = tile << 6;
#pragma unroll
    for (int it = 0; it < 4; ++it) {
        int u = it * 256 + t, row = u >> 4, k = (u & 15) * 8, gr = rbase + row;
        half8 v = {};
        if (gr < NC) {
            int ii = p.cand_i[gr], jj = p.cand_j[gr];
            half8 a = *(const half8*)(p.P1 + (size_t)ii * 128 + k);
            half8 b = *(const half8*)(p.Q1 + (size_t)jj * 128 + k);
#pragma unroll
            for (int x = 0; x < 8; ++x)
                v[x] = (f16)fmaxf((float)a[x] + (float)b[x], 0.f);
        }
        *(half8*)(Abuf + row * SA + k) = v;
    }
    __syncthreads();
    f32x4 acc[4][2];
    {
        float bb0 = p.pred_b2[n0 + mn], bb1 = p.pred_b2[n0 + 16 + mn];
#pragma unroll
        for (int mt = 0; mt < 4; ++mt) {
            acc[mt][0] = (f32x4){bb0, bb0, bb0, bb0};
            acc[mt][1] = (f32x4){bb1, bb1, bb1, bb1};
        }
    }
#pragma unroll
    for (int kc = 0; kc < 4; ++kc) {
        half8 wA = *(const half8*)(p.wt + OFF_PREDW2 + (size_t)(n0 + mn) * 128 + kc * 32 + quad * 8);
        half8 wB = *(const half8*)(p.wt + OFF_PREDW2 + (size_t)(n0 + 16 + mn) * 128 + kc * 32 + quad * 8);
        half8 af[4];
#pragma unroll
        for (int mt = 0; mt < 4; ++mt)
            af[mt] = *(const half8*)(Abuf + (mt * 16 + mn) * SA + kc * 32 + quad * 8);
#pragma unroll
        for (int mt = 0; mt < 4; ++mt) {
            acc[mt][0] = __builtin_amdgcn_mfma_f32_16x16x32_f16(af[mt], wA, acc[mt][0], 0, 0, 0);
            acc[mt][1] = __builtin_amdgcn_mfma_f32_16x16x32_f16(af[mt], wB, acc[mt][1], 0, 0, 0);
        }
    }
    __syncthreads();  // Abuf reads done before aliased Obuf writes
#pragma unroll
    for (int mt = 0; mt < 4; ++mt)
#pragma unroll
        for (int nt = 0; nt < 2; ++nt)
#pragma unroll
            for (int r = 0; r < 4; ++r)
                Obuf[(mt * 16 + quad * 4 + r) * SO + n0 + nt * 16 + mn] =
                    fmaxf(acc[mt][nt][r], 0.f);
    __syncthreads();
    {
        int row = t & 63, q4 = t >> 6;
        float s = 0.f;
#pragma unroll
        for (int i = 0; i < 32; ++i)
            s += Obuf[row * SO + q4 * 32 + i] * w3s[q4 * 32 + i];
        psum[t] = s;
    }
    __syncthreads();
    if (t < 64) {
        int gr = rbase + t;
        if (gr < NC) {
            float lg = psum[t] + psum[t + 64] + psum[t + 128] + psum[t + 192] + b3v;
            p.outL[gr] = lg;
            p.outP[gr] = 1.f / (1.f + expf(-lg));
        }
    }
    __syncthreads();
}

__device__ __forceinline__ void upd_layer_ptrs(const KP& p, int l,
    const f16*& ein, f16*& eout, const f16*& Pin, const f16*& Qin,
    f16*& Pout, f16*& Qout, const f16*& wpq, const float*& bP) {
    ein = (l & 1) ? p.eB : p.eA;
    eout = (l & 1) ? p.eA : p.eB;
    Pin = (l & 1) ? p.P1 : p.P0;
    Qin = (l & 1) ? p.Q1 : p.Q0;
    Pout = (l & 1) ? p.P0 : p.P1;
    Qout = (l & 1) ? p.Q0 : p.Q1;
    wpq = (l < 2) ? (p.wt + OFF_MSGPQ + (l + 1) * 32768) : (p.wt + OFF_PREDPQ);
    bP = (l < 2) ? (p.msg_b1 + (l + 1) * 128) : p.pred_b1;
}

// ---------------- cooperative single-launch path ----------------
__global__ __launch_bounds__(256, 2) void gnn_all(KP p) {
    cg::grid_group gg = cg::this_grid();
    __shared__ __align__(16) char SMEM[34816];
    __shared__ float w3s[128];
    __shared__ float psum[256];
    const int t = threadIdx.x;
    const int gsz = gridDim.x * 256;
    const int g0 = blockIdx.x * 256 + t;

    for (int gid = g0; gid < PTOT; gid += gsz) prep_item(p, gid);
    gg.sync();

    for (int tile = blockIdx.x; tile < (NE + 63) / 64; tile += gridDim.x)
        do_tile<64, false>(SMEM, tile, p.xb, nullptr, nullptr, nullptr, nullptr, nullptr,
                           p.wt + OFF_ENC1, 64, p.enc_b1, p.wt + OFF_ENC2, p.enc_b2, false,
                           p.eA, p.wt + OFF_MSGPQ, p.msg_b1, p.P0, p.Q0);
    for (int i = g0; i < NA; i += gsz) degseg_item(p, i);

    for (int l = 0; l < 3; ++l) {
        gg.sync();
        const f16 *ein, *Pin, *Qin, *wpq;
        f16 *eout, *Pout, *Qout;
        const float* bP;
        upd_layer_ptrs(p, l, ein, eout, Pin, Qin, Pout, Qout, wpq, bP);
        for (int tile = blockIdx.x; tile < (NE + 63) / 64; tile += gridDim.x)
            do_tile<256, true>(SMEM, tile, ein, Pin, Qin, p.adj_src, p.segStart, p.segEnd,
                               p.wt + OFF_UPD1 + l * 32768, 256, p.fbias + l * 128,
                               p.wt + OFF_UPD2 + l * 16384, p.upd_b2 + l * 128, true,
                               eout, wpq, bP, Pout, Qout);
    }
    gg.sync();

    if (t < 128) w3s[t] = p.pred_W3[t];
    float b3v = p.pred_b3[0];
    for (int tile = blockIdx.x; tile < (NC + 63) / 64; tile += gridDim.x)
        pred_tile(p, SMEM, w3s, psum, tile, b3v);
}

// ---------------- fallback multi-launch path (same device bodies) ----------------
__global__ void k_prep(KP p) {
    int gid = blockIdx.x * 256 + threadIdx.x;
    if (gid < PTOT) prep_item(p, gid);
}
__global__ void k_degseg(KP p) {
    int i = blockIdx.x * 256 + threadIdx.x;
    if (i < NA) degseg_item(p, i);
}
__global__ __launch_bounds__(256, 2) void k_enc(KP p) {
    __shared__ __align__(16) char SMEM[34816];
    do_tile<64, false>(SMEM, blockIdx.x, p.xb, nullptr, nullptr, nullptr, nullptr, nullptr,
                       p.wt + OFF_ENC1, 64, p.enc_b1, p.wt + OFF_ENC2, p.enc_b2, false,
                       p.eA, p.wt + OFF_MSGPQ, p.msg_b1, p.P0, p.Q0);
}
__global__ __launch_bounds__(256, 2) void k_upd(KP p, int l) {
    __shared__ __align__(16) char SMEM[34816];
    const f16 *ein, *Pin, *Qin, *wpq;
    f16 *eout, *Pout, *Qout;
    const float* bP;
    upd_layer_ptrs(p, l, ein, eout, Pin, Qin, Pout, Qout, wpq, bP);
    do_tile<256, true>(SMEM, blockIdx.x, ein, Pin, Qin, p.adj_src, p.segStart, p.segEnd,
                       p.wt + OFF_UPD1 + l * 32768, 256, p.fbias + l * 128,
                       p.wt + OFF_UPD2 + l * 16384, p.upd_b2 + l * 128, true,
                       eout, wpq, bP, Pout, Qout);
}
__global__ __launch_bounds__(256, 2) void k_pred(KP p) {
    __shared__ __align__(16) char SMEM[34816];
    __shared__ float w3s[128];
    __shared__ float psum[256];
    if (threadIdx.x < 128) w3s[threadIdx.x] = p.pred_W3[threadIdx.x];
    float b3v = p.pred_b3[0];
    pred_tile(p, SMEM, w3s, psum, blockIdx.x, b3v);
}

// ---------------- host ----------------
extern "C" void kernel_launch(void* const* d_in, const int* in_sizes, int n_in,
                              void* d_out, int out_size, void* d_ws, size_t ws_size,
                              hipStream_t stream) {
    KP p;
    p.edge_features = (const float*)d_in[0];
    p.adj_dst = (const int*)d_in[1];
    p.adj_src = (const int*)d_in[2];
    p.cand_i = (const int*)d_in[3];
    p.cand_j = (const int*)d_in[4];
    const float* enc_W1 = (const float*)d_in[5];
    p.enc_b1 = (const float*)d_in[6];
    const float* enc_W2 = (const float*)d_in[7];
    p.enc_b2 = (const float*)d_in[8];
    const float* msg_W1 = (const float*)d_in[9];
    p.msg_b1 = (const float*)d_in[10];
    p.msg_W2 = (const float*)d_in[11];
    p.msg_b2 = (const float*)d_in[12];
    p.upd_W1 = (const float*)d_in[13];
    p.upd_b1 = (const float*)d_in[14];
    const float* upd_W2 = (const float*)d_in[15];
    p.upd_b2 = (const float*)d_in[16];
    const float* pred_W1 = (const float*)d_in[17];
    p.pred_b1 = (const float*)d_in[18];
    const float* pred_W2 = (const float*)d_in[19];
    p.pred_b2 = (const float*)d_in[20];
    p.pred_W3 = (const float*)d_in[21];
    p.pred_b3 = (const float*)d_in[22];

    char* ws = (char*)d_ws;
    size_t off = 0;
    auto alloc = [&](size_t bytes) -> void* {
        void* q = ws + off;
        off = (off + bytes + 255) & ~(size_t)255;
        return q;
    };
    p.wt = (f16*)alloc((size_t)TOTAL_WT * 2);
    p.fbias = (float*)alloc(3 * 128 * 4);
    p.xb = (f16*)alloc((size_t)NE * 64 * 2);
    p.eA = (f16*)alloc((size_t)NE * 128 * 2);
    p.eB = (f16*)alloc((size_t)NE * 128 * 2);
    p.P0 = (f16*)alloc((size_t)NE * 128 * 2);
    p.Q0 = (f16*)alloc((size_t)NE * 128 * 2);
    p.P1 = (f16*)alloc((size_t)NE * 128 * 2);
    p.Q1 = (f16*)alloc((size_t)NE * 128 * 2);
    p.segStart = (int*)alloc((size_t)NE * 4);
    p.segEnd = (int*)alloc((size_t)NE * 4);
    p.outP = (float*)d_out;
    p.outL = (float*)d_out + NC;

    int idx = 0, c = 0;
    auto addj = [&](const float* s, int K, int o, int st) {
        p.wsrc[idx] = s; p.wK[idx] = K; p.wOff[idx] = o;
        p.wStr[idx] = st; p.wCum[idx] = c;
        c += K * 128; idx++;
    };
    addj(enc_W1, 64, OFF_ENC1, 64);
    addj(enc_W2, 128, OFF_ENC2, 128);
    for (int l = 0; l < 3; ++l) addj(msg_W1 + (size_t)l * 32768, 128, OFF_MSGPQ + l * 32768, 128);
    for (int l = 0; l < 3; ++l) addj(msg_W1 + (size_t)l * 32768 + 16384, 128, OFF_MSGPQ + l * 32768 + 16384, 128);
    for (int l = 0; l < 3; ++l) addj(p.upd_W1 + (size_t)l * 32768, 128, OFF_UPD1 + l * 32768, 256);
    for (int l = 0; l < 3; ++l) addj(upd_W2 + (size_t)l * 16384, 128, OFF_UPD2 + l * 16384, 128);
    addj(pred_W1, 128, OFF_PREDPQ, 128);
    addj(pred_W1 + 16384, 128, OFF_PREDPQ + 16384, 128);
    addj(pred_W2, 128, OFF_PREDW2, 128);
    for (int i = idx; i <= 20; ++i) p.wCum[i] = c;  // c == 270336 == R_WT

    // 512 blocks = 2/CU: co-residency guaranteed by __launch_bounds__(256,2)
    // (VGPR capped for 2 blocks/CU; LDS 2x36.4KB << 160KB). No occupancy API.
    void* args[] = {(void*)&p};
    hipError_t le = hipLaunchCooperativeKernel(gnn_all, dim3(512), dim3(256), args, 0, stream);
    if (le != hipSuccess) {
        (void)hipGetLastError();  // clear sticky error; use plain-launch fallback
        const int tilesNE = (NE + 63) / 64;   // 782
        const int tilesNC = (NC + 63) / 64;   // 1563
        k_prep<<<(PTOT + 255) / 256, 256, 0, stream>>>(p);
        k_degseg<<<(NA + 255) / 256, 256, 0, stream>>>(p);
        k_enc<<<tilesNE, 256, 0, stream>>>(p);
        for (int l = 0; l < 3; ++l) k_upd<<<tilesNE, 256, 0, stream>>>(p, l);
        k_pred<<<tilesNC, 256, 0, stream>>>(p);
    }

    (void)in_sizes; (void)n_in; (void)out_size; (void)ws_size;
}

// Round 6
// 438.626 us; speedup vs baseline: 2.1216x; 2.1216x over previous
//
#include <hip/hip_runtime.h>
#include <hip/hip_bf16.h>

#define NE 50000
#define NA 800000
#define NC 100000

typedef _Float16 f16;
typedef f16 half8 __attribute__((ext_vector_type(8)));
typedef f16 f16x2 __attribute__((ext_vector_type(2)));
typedef float f32x4 __attribute__((ext_vector_type(4)));

// f16-element offsets inside the converted-weight arena
#define OFF_ENC1 0
#define OFF_ENC2 8192
#define OFF_MSGPQ 24576    // 3 layers x 32768 (P block 16384 + Q block 16384)
#define OFF_UPD1 122880    // 3 layers x 32768, fused layout [n][256]
#define OFF_UPD2 221184    // 3 layers x 16384
#define OFF_PREDPQ 270336  // 32768
#define OFF_PREDW2 303104  // 16384
#define TOTAL_WT 319488

#define R_FUSE 49536       // 3*129 groups x 128 threads
#define R_WT 270336
#define R_X 800000         // NE*64/4
#define R_Z 50000
#define PTOT (R_FUSE + R_WT + R_X + R_Z)

struct KP {
    const float* edge_features;
    const int *adj_dst, *adj_src, *cand_i, *cand_j;
    const float *enc_b1, *enc_b2;
    const float *msg_b1, *msg_W2, *msg_b2;
    const float *upd_W1, *upd_b1, *upd_b2;
    const float *pred_b1, *pred_b2, *pred_W3, *pred_b3;
    f16* wt;
    float* fbias;
    f16 *xb, *eA, *eB, *P0, *Q0, *P1, *Q1;
    int *segStart, *segEnd;
    float *outP, *outL;
    const float* wsrc[20];
    int wK[20], wOff[20], wStr[20], wCum[21];
};

// ---------------- shared device bodies ----------------

__device__ __forceinline__ void prep_item(const KP& p, int gid) {
    if (gid < R_FUSE) {
        // fused W2U = msg_W2 @ upd_W1[128:256] and fbias; coalesced per 128-group
        int g = gid >> 7, n = gid & 127;
        int l = g / 129, kk = g % 129;
        const float* U1b = p.upd_W1 + (size_t)l * 32768 + 16384;
        if (kk < 128) {
            const float* w2row = p.msg_W2 + (size_t)l * 16384 + (size_t)kk * 128;
            float s = 0.f;
            for (int m = 0; m < 128; ++m) s += w2row[m] * U1b[m * 128 + n];
            p.wt[OFF_UPD1 + l * 32768 + n * 256 + 128 + kk] = (f16)s;
        } else {
            const float* b2 = p.msg_b2 + l * 128;
            float s = p.upd_b1[l * 128 + n];
            for (int m = 0; m < 128; ++m) s += b2[m] * U1b[m * 128 + n];
            p.fbias[l * 128 + n] = s;
        }
    } else if (gid < R_FUSE + R_WT) {
        int e = gid - R_FUSE;
        int j = 0;
#pragma unroll
        for (int i = 1; i < 20; ++i) j += (e >= p.wCum[i]) ? 1 : 0;
        int r = e - p.wCum[j];
        int K = p.wK[j];
        int k = r % K, n = r / K;
        p.wt[p.wOff[j] + n * p.wStr[j] + k] = (f16)p.wsrc[j][(size_t)k * 128 + n];
    } else if (gid < R_FUSE + R_WT + R_X) {
        int g2 = gid - (R_FUSE + R_WT);
        float4 v = ((const float4*)p.edge_features)[g2];
        f16x2 a = {(f16)v.x, (f16)v.y}, b = {(f16)v.z, (f16)v.w};
        ((f16x2*)p.xb)[g2 * 2] = a;
        ((f16x2*)p.xb)[g2 * 2 + 1] = b;
    } else if (gid < PTOT) {
        int z = gid - (R_FUSE + R_WT + R_X);
        p.segStart[z] = 0;
        p.segEnd[z] = 0;
    }
}

__device__ __forceinline__ void degseg_item(const KP& p, int i) {
    int d = p.adj_dst[i];
    if (i == 0 || p.adj_dst[i - 1] != d) p.segStart[d] = i;
    if (i == NA - 1 || p.adj_dst[i + 1] != d) p.segEnd[d] = i + 1;
}

// one 64-row tile: [agg into A-right]? -> GEMM1(K1) -> relu -> GEMM2 -> e' -> P/Q GEMMs
template <int K1, bool AGG>
__device__ __forceinline__ void do_tile(
    char* SMEM, int tile, const f16* __restrict__ in0,
    const f16* __restrict__ Pin, const f16* __restrict__ Qin,
    const int* __restrict__ adj_src, const int* __restrict__ segStart,
    const int* __restrict__ segEnd,
    const f16* __restrict__ w1t, const int w1s, const float* __restrict__ b1v,
    const f16* __restrict__ w2t, const float* __restrict__ b2v, const bool reluOut,
    f16* __restrict__ oute,
    const f16* __restrict__ wpq, const float* __restrict__ bPp,
    f16* __restrict__ Pout, f16* __restrict__ Qout) {
    constexpr int SA = K1 + 8;   // f16 stride
    constexpr int SH = 136;      // f16 stride for H/E
    f16* Abuf = (f16*)SMEM;
    f16* Hbuf = (f16*)SMEM;                  // aliases Abuf low (dead after GEMM1)
    f16* Ebuf = (f16*)(SMEM + 17408);        // disjoint from Hbuf
    const int t = threadIdx.x, lane = t & 63, wave = t >> 6;
    const int quad = lane >> 4, mn = lane & 15, n0 = wave * 32;
    const int rbase = tile << 6;

    // ---- stage A-tile (left half from global; right half from in-wave agg)
    if constexpr (K1 == 64) {
#pragma unroll
        for (int it = 0; it < 2; ++it) {
            int u = it * 256 + t, row = u >> 3, k = (u & 7) * 8, gr = rbase + row;
            half8 v = {};
            if (gr < NE) v = *(const half8*)(in0 + (size_t)gr * 64 + k);
            *(half8*)(Abuf + row * SA + k) = v;
        }
    } else {
#pragma unroll
        for (int it = 0; it < 4; ++it) {
            int u = it * 256 + t, row = u >> 4, k = (u & 15) * 8, gr = rbase + row;
            half8 v = {};
            if (gr < NE) v = *(const half8*)(in0 + (size_t)gr * 128 + k);
            *(half8*)(Abuf + row * SA + k) = v;
        }
    }
    if constexpr (AGG) {
        // wave computes hbar for its 16 rows: inv_deg * sum relu(P[dst]+Q[src])
        for (int i = 0; i < 16; ++i) {
            int dst = rbase + wave * 16 + i;
            float a0 = 0.f, a1 = 0.f;
            if (dst < NE) {
                f16x2 p2 = ((const f16x2*)Pin)[(size_t)dst * 64 + lane];
                float pp0 = (float)p2.x, pp1 = (float)p2.y;
                int s = segStart[dst];
                int deg = segEnd[dst] - s;
                if (deg == 0) {
                    f16x2 q2 = ((const f16x2*)Qin)[(size_t)dst * 64 + lane];
                    a0 = fmaxf(pp0 + (float)q2.x, 0.f);
                    a1 = fmaxf(pp1 + (float)q2.y, 0.f);
                } else {
                    float x0 = 0.f, x1 = 0.f;
                    int j = 0;
                    for (; j + 7 < deg; j += 8) {
                        f16x2 q[8];
#pragma unroll
                        for (int u2 = 0; u2 < 8; ++u2)
                            q[u2] = ((const f16x2*)Qin)[(size_t)adj_src[s + j + u2] * 64 + lane];
#pragma unroll
                        for (int u2 = 0; u2 < 8; ++u2) {
                            x0 += fmaxf(pp0 + (float)q[u2].x, 0.f);
                            x1 += fmaxf(pp1 + (float)q[u2].y, 0.f);
                        }
                    }
                    for (; j < deg; ++j) {
                        f16x2 q2 = ((const f16x2*)Qin)[(size_t)adj_src[s + j] * 64 + lane];
                        x0 += fmaxf(pp0 + (float)q2.x, 0.f);
                        x1 += fmaxf(pp1 + (float)q2.y, 0.f);
                    }
                    float sc = 1.f / (float)deg;
                    a0 = x0 * sc;
                    a1 = x1 * sc;
                }
            }
            f16x2 o = {(f16)a0, (f16)a1};
            *(f16x2*)(Abuf + (wave * 16 + i) * SA + 128 + lane * 2) = o;
        }
    }
    __syncthreads();

    // ---- GEMM1: [64 x K1] @ [K1 x 128] + b1, relu -> Hbuf
    f32x4 acc[4][2];
    {
        float bb0 = b1v[n0 + mn], bb1 = b1v[n0 + 16 + mn];
#pragma unroll
        for (int mt = 0; mt < 4; ++mt) {
            acc[mt][0] = (f32x4){bb0, bb0, bb0, bb0};
            acc[mt][1] = (f32x4){bb1, bb1, bb1, bb1};
        }
    }
#pragma unroll
    for (int kc = 0; kc < K1 / 32; ++kc) {
        half8 wA = *(const half8*)(w1t + (size_t)(n0 + mn) * w1s + kc * 32 + quad * 8);
        half8 wB = *(const half8*)(w1t + (size_t)(n0 + 16 + mn) * w1s + kc * 32 + quad * 8);
        half8 af[4];
#pragma unroll
        for (int mt = 0; mt < 4; ++mt)
            af[mt] = *(const half8*)(Abuf + (mt * 16 + mn) * SA + kc * 32 + quad * 8);
#pragma unroll
        for (int mt = 0; mt < 4; ++mt) {
            acc[mt][0] = __builtin_amdgcn_mfma_f32_16x16x32_f16(af[mt], wA, acc[mt][0], 0, 0, 0);
            acc[mt][1] = __builtin_amdgcn_mfma_f32_16x16x32_f16(af[mt], wB, acc[mt][1], 0, 0, 0);
        }
    }
    __syncthreads();  // A reads done before aliased Hbuf writes
#pragma unroll
    for (int mt = 0; mt < 4; ++mt)
#pragma unroll
        for (int nt = 0; nt < 2; ++nt)
#pragma unroll
            for (int r = 0; r < 4; ++r)
                Hbuf[(mt * 16 + quad * 4 + r) * SH + n0 + nt * 16 + mn] =
                    (f16)fmaxf(acc[mt][nt][r], 0.f);
    __syncthreads();

    // ---- GEMM2: [64x128]@[128x128] + b2 (+relu) -> Ebuf
    {
        float bb0 = b2v[n0 + mn], bb1 = b2v[n0 + 16 + mn];
#pragma unroll
        for (int mt = 0; mt < 4; ++mt) {
            acc[mt][0] = (f32x4){bb0, bb0, bb0, bb0};
            acc[mt][1] = (f32x4){bb1, bb1, bb1, bb1};
        }
    }
#pragma unroll
    for (int kc = 0; kc < 4; ++kc) {
        half8 wA = *(const half8*)(w2t + (size_t)(n0 + mn) * 128 + kc * 32 + quad * 8);
        half8 wB = *(const half8*)(w2t + (size_t)(n0 + 16 + mn) * 128 + kc * 32 + quad * 8);
        half8 af[4];
#pragma unroll
        for (int mt = 0; mt < 4; ++mt)
            af[mt] = *(const half8*)(Hbuf + (mt * 16 + mn) * SH + kc * 32 + quad * 8);
#pragma unroll
        for (int mt = 0; mt < 4; ++mt) {
            acc[mt][0] = __builtin_amdgcn_mfma_f32_16x16x32_f16(af[mt], wA, acc[mt][0], 0, 0, 0);
            acc[mt][1] = __builtin_amdgcn_mfma_f32_16x16x32_f16(af[mt], wB, acc[mt][1], 0, 0, 0);
        }
    }
#pragma unroll
    for (int mt = 0; mt < 4; ++mt)
#pragma unroll
        for (int nt = 0; nt < 2; ++nt)
#pragma unroll
            for (int r = 0; r < 4; ++r) {
                float v = acc[mt][nt][r];
                if (reluOut) v = fmaxf(v, 0.f);
                Ebuf[(mt * 16 + quad * 4 + r) * SH + n0 + nt * 16 + mn] = (f16)v;
            }
    __syncthreads();  // Ebuf ready

    // ---- vectorized e' store from Ebuf
#pragma unroll
    for (int it = 0; it < 4; ++it) {
        int u = it * 256 + t, row = u >> 4, k = (u & 15) * 8, gr = rbase + row;
        if (gr < NE) {
            half8 v = *(const half8*)(Ebuf + row * SH + k);
            *(half8*)(oute + (size_t)gr * 128 + k) = v;
        }
    }

    // ---- P GEMM (bias) then Q GEMM (no bias) on e'
    {
        float bb0 = bPp[n0 + mn], bb1 = bPp[n0 + 16 + mn];
#pragma unroll
        for (int mt = 0; mt < 4; ++mt) {
            acc[mt][0] = (f32x4){bb0, bb0, bb0, bb0};
            acc[mt][1] = (f32x4){bb1, bb1, bb1, bb1};
        }
    }
#pragma unroll
    for (int kc = 0; kc < 4; ++kc) {
        half8 wA = *(const half8*)(wpq + (size_t)(n0 + mn) * 128 + kc * 32 + quad * 8);
        half8 wB = *(const half8*)(wpq + (size_t)(n0 + 16 + mn) * 128 + kc * 32 + quad * 8);
        half8 af[4];
#pragma unroll
        for (int mt = 0; mt < 4; ++mt)
            af[mt] = *(const half8*)(Ebuf + (mt * 16 + mn) * SH + kc * 32 + quad * 8);
#pragma unroll
        for (int mt = 0; mt < 4; ++mt) {
            acc[mt][0] = __builtin_amdgcn_mfma_f32_16x16x32_f16(af[mt], wA, acc[mt][0], 0, 0, 0);
            acc[mt][1] = __builtin_amdgcn_mfma_f32_16x16x32_f16(af[mt], wB, acc[mt][1], 0, 0, 0);
        }
    }
#pragma unroll
    for (int mt = 0; mt < 4; ++mt)
#pragma unroll
        for (int nt = 0; nt < 2; ++nt)
#pragma unroll
            for (int r = 0; r < 4; ++r) {
                int gr = rbase + mt * 16 + quad * 4 + r;
                if (gr < NE)
                    Pout[(size_t)gr * 128 + n0 + nt * 16 + mn] = (f16)acc[mt][nt][r];
            }
#pragma unroll
    for (int mt = 0; mt < 4; ++mt) {
        acc[mt][0] = (f32x4){0.f, 0.f, 0.f, 0.f};
        acc[mt][1] = (f32x4){0.f, 0.f, 0.f, 0.f};
    }
#pragma unroll
    for (int kc = 0; kc < 4; ++kc) {
        half8 wA = *(const half8*)(wpq + 16384 + (size_t)(n0 + mn) * 128 + kc * 32 + quad * 8);
        half8 wB = *(const half8*)(wpq + 16384 + (size_t)(n0 + 16 + mn) * 128 + kc * 32 + quad * 8);
        half8 af[4];
#pragma unroll
        for (int mt = 0; mt < 4; ++mt)
            af[mt] = *(const half8*)(Ebuf + (mt * 16 + mn) * SH + kc * 32 + quad * 8);
#pragma unroll
        for (int mt = 0; mt < 4; ++mt) {
            acc[mt][0] = __builtin_amdgcn_mfma_f32_16x16x32_f16(af[mt], wA, acc[mt][0], 0, 0, 0);
            acc[mt][1] = __builtin_amdgcn_mfma_f32_16x16x32_f16(af[mt], wB, acc[mt][1], 0, 0, 0);
        }
    }
#pragma unroll
    for (int mt = 0; mt < 4; ++mt)
#pragma unroll
        for (int nt = 0; nt < 2; ++nt)
#pragma unroll
            for (int r = 0; r < 4; ++r) {
                int gr = rbase + mt * 16 + quad * 4 + r;
                if (gr < NE)
                    Qout[(size_t)gr * 128 + n0 + nt * 16 + mn] = (f16)acc[mt][nt][r];
            }
}

// one predictor tile: h1=relu(P1[i]+Q1[j]); h2=relu(h1@W2+b2); logit=h2@w3+b3; sigmoid
__device__ __forceinline__ void pred_tile(const KP& p, char* SMEM, float* w3s,
                                          float* psum, int tile, float b3v) {
    constexpr int SA = 136, SO = 133;
    f16* Abuf = (f16*)SMEM;
    float* Obuf = (float*)SMEM;
    const int t = threadIdx.x, lane = t & 63, wave = t >> 6;
    const int quad = lane >> 4, mn = lane & 15, n0 = wave * 32;
    const int rbase = tile << 6;
#pragma unroll
    for (int it = 0; it < 4; ++it) {
        int u = it * 256 + t, row = u >> 4, k = (u & 15) * 8, gr = rbase + row;
        half8 v = {};
        if (gr < NC) {
            int ii = p.cand_i[gr], jj = p.cand_j[gr];
            half8 a = *(const half8*)(p.P1 + (size_t)ii * 128 + k);
            half8 b = *(const half8*)(p.Q1 + (size_t)jj * 128 + k);
#pragma unroll
            for (int x = 0; x < 8; ++x)
                v[x] = (f16)fmaxf((float)a[x] + (float)b[x], 0.f);
        }
        *(half8*)(Abuf + row * SA + k) = v;
    }
    __syncthreads();
    f32x4 acc[4][2];
    {
        float bb0 = p.pred_b2[n0 + mn], bb1 = p.pred_b2[n0 + 16 + mn];
#pragma unroll
        for (int mt = 0; mt < 4; ++mt) {
            acc[mt][0] = (f32x4){bb0, bb0, bb0, bb0};
            acc[mt][1] = (f32x4){bb1, bb1, bb1, bb1};
        }
    }
#pragma unroll
    for (int kc = 0; kc < 4; ++kc) {
        half8 wA = *(const half8*)(p.wt + OFF_PREDW2 + (size_t)(n0 + mn) * 128 + kc * 32 + quad * 8);
        half8 wB = *(const half8*)(p.wt + OFF_PREDW2 + (size_t)(n0 + 16 + mn) * 128 + kc * 32 + quad * 8);
        half8 af[4];
#pragma unroll
        for (int mt = 0; mt < 4; ++mt)
            af[mt] = *(const half8*)(Abuf + (mt * 16 + mn) * SA + kc * 32 + quad * 8);
#pragma unroll
        for (int mt = 0; mt < 4; ++mt) {
            acc[mt][0] = __builtin_amdgcn_mfma_f32_16x16x32_f16(af[mt], wA, acc[mt][0], 0, 0, 0);
            acc[mt][1] = __builtin_amdgcn_mfma_f32_16x16x32_f16(af[mt], wB, acc[mt][1], 0, 0, 0);
        }
    }
    __syncthreads();  // Abuf reads done before aliased Obuf writes
#pragma unroll
    for (int mt = 0; mt < 4; ++mt)
#pragma unroll
        for (int nt = 0; nt < 2; ++nt)
#pragma unroll
            for (int r = 0; r < 4; ++r)
                Obuf[(mt * 16 + quad * 4 + r) * SO + n0 + nt * 16 + mn] =
                    fmaxf(acc[mt][nt][r], 0.f);
    __syncthreads();
    {
        int row = t & 63, q4 = t >> 6;
        float s = 0.f;
#pragma unroll
        for (int i = 0; i < 32; ++i)
            s += Obuf[row * SO + q4 * 32 + i] * w3s[q4 * 32 + i];
        psum[t] = s;
    }
    __syncthreads();
    if (t < 64) {
        int gr = rbase + t;
        if (gr < NC) {
            float lg = psum[t] + psum[t + 64] + psum[t + 128] + psum[t + 192] + b3v;
            p.outL[gr] = lg;
            p.outP[gr] = 1.f / (1.f + expf(-lg));
        }
    }
}

__device__ __forceinline__ void upd_layer_ptrs(const KP& p, int l,
    const f16*& ein, f16*& eout, const f16*& Pin, const f16*& Qin,
    f16*& Pout, f16*& Qout, const f16*& wpq, const float*& bP) {
    ein = (l & 1) ? p.eB : p.eA;
    eout = (l & 1) ? p.eA : p.eB;
    Pin = (l & 1) ? p.P1 : p.P0;
    Qin = (l & 1) ? p.Q1 : p.Q0;
    Pout = (l & 1) ? p.P0 : p.P1;
    Qout = (l & 1) ? p.Q0 : p.Q1;
    wpq = (l < 2) ? (p.wt + OFF_MSGPQ + (l + 1) * 32768) : (p.wt + OFF_PREDPQ);
    bP = (l < 2) ? (p.msg_b1 + (l + 1) * 128) : p.pred_b1;
}

// ---------------- plain launches, high occupancy ----------------
__global__ void k_prep(KP p) {
    int gid = blockIdx.x * 256 + threadIdx.x;
    if (gid < PTOT) prep_item(p, gid);
}
// encoder + PQ0 tile, then grid-stride degseg over NA (same launch; agg reads next launch)
__global__ __launch_bounds__(256, 4) void k_encdeg(KP p) {
    __shared__ __align__(16) char SMEM[34816];
    do_tile<64, false>(SMEM, blockIdx.x, p.xb, nullptr, nullptr, nullptr, nullptr, nullptr,
                       p.wt + OFF_ENC1, 64, p.enc_b1, p.wt + OFF_ENC2, p.enc_b2, false,
                       p.eA, p.wt + OFF_MSGPQ, p.msg_b1, p.P0, p.Q0);
    const int nthr = gridDim.x * 256;
    for (int i = blockIdx.x * 256 + threadIdx.x; i < NA; i += nthr) degseg_item(p, i);
}
__global__ __launch_bounds__(256, 4) void k_upd(KP p, int l) {
    __shared__ __align__(16) char SMEM[34816];
    const f16 *ein, *Pin, *Qin, *wpq;
    f16 *eout, *Pout, *Qout;
    const float* bP;
    upd_layer_ptrs(p, l, ein, eout, Pin, Qin, Pout, Qout, wpq, bP);
    do_tile<256, true>(SMEM, blockIdx.x, ein, Pin, Qin, p.adj_src, p.segStart, p.segEnd,
                       p.wt + OFF_UPD1 + l * 32768, 256, p.fbias + l * 128,
                       p.wt + OFF_UPD2 + l * 16384, p.upd_b2 + l * 128, true,
                       eout, wpq, bP, Pout, Qout);
}
__global__ __launch_bounds__(256, 4) void k_pred(KP p) {
    __shared__ __align__(16) char SMEM[34816];
    __shared__ float w3s[128];
    __shared__ float psum[256];
    if (threadIdx.x < 128) w3s[threadIdx.x] = p.pred_W3[threadIdx.x];
    float b3v = p.pred_b3[0];
    pred_tile(p, SMEM, w3s, psum, blockIdx.x, b3v);
}

// ---------------- host ----------------
extern "C" void kernel_launch(void* const* d_in, const int* in_sizes, int n_in,
                              void* d_out, int out_size, void* d_ws, size_t ws_size,
                              hipStream_t stream) {
    KP p;
    p.edge_features = (const float*)d_in[0];
    p.adj_dst = (const int*)d_in[1];
    p.adj_src = (const int*)d_in[2];
    p.cand_i = (const int*)d_in[3];
    p.cand_j = (const int*)d_in[4];
    const float* enc_W1 = (const float*)d_in[5];
    p.enc_b1 = (const float*)d_in[6];
    const float* enc_W2 = (const float*)d_in[7];
    p.enc_b2 = (const float*)d_in[8];
    const float* msg_W1 = (const float*)d_in[9];
    p.msg_b1 = (const float*)d_in[10];
    p.msg_W2 = (const float*)d_in[11];
    p.msg_b2 = (const float*)d_in[12];
    p.upd_W1 = (const float*)d_in[13];
    p.upd_b1 = (const float*)d_in[14];
    const float* upd_W2 = (const float*)d_in[15];
    p.upd_b2 = (const float*)d_in[16];
    const float* pred_W1 = (const float*)d_in[17];
    p.pred_b1 = (const float*)d_in[18];
    const float* pred_W2 = (const float*)d_in[19];
    p.pred_b2 = (const float*)d_in[20];
    p.pred_W3 = (const float*)d_in[21];
    p.pred_b3 = (const float*)d_in[22];

    char* ws = (char*)d_ws;
    size_t off = 0;
    auto alloc = [&](size_t bytes) -> void* {
        void* q = ws + off;
        off = (off + bytes + 255) & ~(size_t)255;
        return q;
    };
    p.wt = (f16*)alloc((size_t)TOTAL_WT * 2);
    p.fbias = (float*)alloc(3 * 128 * 4);
    p.xb = (f16*)alloc((size_t)NE * 64 * 2);
    p.eA = (f16*)alloc((size_t)NE * 128 * 2);
    p.eB = (f16*)alloc((size_t)NE * 128 * 2);
    p.P0 = (f16*)alloc((size_t)NE * 128 * 2);
    p.Q0 = (f16*)alloc((size_t)NE * 128 * 2);
    p.P1 = (f16*)alloc((size_t)NE * 128 * 2);
    p.Q1 = (f16*)alloc((size_t)NE * 128 * 2);
    p.segStart = (int*)alloc((size_t)NE * 4);
    p.segEnd = (int*)alloc((size_t)NE * 4);
    p.outP = (float*)d_out;
    p.outL = (float*)d_out + NC;

    int idx = 0, c = 0;
    auto addj = [&](const float* s, int K, int o, int st) {
        p.wsrc[idx] = s; p.wK[idx] = K; p.wOff[idx] = o;
        p.wStr[idx] = st; p.wCum[idx] = c;
        c += K * 128; idx++;
    };
    addj(enc_W1, 64, OFF_ENC1, 64);
    addj(enc_W2, 128, OFF_ENC2, 128);
    for (int l = 0; l < 3; ++l) addj(msg_W1 + (size_t)l * 32768, 128, OFF_MSGPQ + l * 32768, 128);
    for (int l = 0; l < 3; ++l) addj(msg_W1 + (size_t)l * 32768 + 16384, 128, OFF_MSGPQ + l * 32768 + 16384, 128);
    for (int l = 0; l < 3; ++l) addj(p.upd_W1 + (size_t)l * 32768, 128, OFF_UPD1 + l * 32768, 256);
    for (int l = 0; l < 3; ++l) addj(upd_W2 + (size_t)l * 16384, 128, OFF_UPD2 + l * 16384, 128);
    addj(pred_W1, 128, OFF_PREDPQ, 128);
    addj(pred_W1 + 16384, 128, OFF_PREDPQ + 16384, 128);
    addj(pred_W2, 128, OFF_PREDW2, 128);
    for (int i = idx; i <= 20; ++i) p.wCum[i] = c;  // c == 270336 == R_WT

    const int tilesNE = (NE + 63) / 64;   // 782
    const int tilesNC = (NC + 63) / 64;   // 1563
    k_prep<<<(PTOT + 255) / 256, 256, 0, stream>>>(p);
    k_encdeg<<<tilesNE, 256, 0, stream>>>(p);
    for (int l = 0; l < 3; ++l) k_upd<<<tilesNE, 256, 0, stream>>>(p, l);
    k_pred<<<tilesNC, 256, 0, stream>>>(p);

    (void)in_sizes; (void)n_in; (void)out_size; (void)ws_size;
}

// Round 7
// 392.512 us; speedup vs baseline: 2.3709x; 1.1175x over previous
//
#include <hip/hip_runtime.h>
#include <hip/hip_bf16.h>

#define NE 50000
#define NA 800000
#define NC 100000

typedef _Float16 f16;
typedef f16 half8 __attribute__((ext_vector_type(8)));
typedef f16 f16x2 __attribute__((ext_vector_type(2)));
typedef float f32x4 __attribute__((ext_vector_type(4)));

// f16-element offsets inside the converted-weight arena
#define OFF_ENC1 0
#define OFF_ENC2 8192
#define OFF_MSGPQ 24576    // 3 layers x 32768 (P block 16384 + Q block 16384)
#define OFF_UPD1 122880    // 3 layers x 32768, fused layout [n][256]
#define OFF_UPD2 221184    // 3 layers x 16384
#define OFF_PREDPQ 270336  // 32768
#define OFF_PREDW2 303104  // 16384
#define TOTAL_WT 319488

#define R_FUSE 49536       // 3*129 groups x 128 threads
#define R_WT 270336
#define R_X 800000         // NE*64/4
#define R_Z 50000
#define PTOT (R_FUSE + R_WT + R_X + R_Z)

struct KP {
    const float* edge_features;
    const int *adj_dst, *adj_src, *cand_i, *cand_j;
    const float *enc_b1, *enc_b2;
    const float *msg_b1, *msg_W2, *msg_b2;
    const float *upd_W1, *upd_b1, *upd_b2;
    const float *pred_b1, *pred_b2, *pred_W3, *pred_b3;
    f16* wt;
    float* fbias;
    f16 *xb, *eA, *eB, *P0, *Q0, *P1, *Q1;
    int *segStart, *segEnd;
    float *outP, *outL;
    const float* wsrc[20];
    int wK[20], wOff[20], wStr[20], wCum[21];
};

// ---------------- shared device bodies ----------------

__device__ __forceinline__ void prep_item(const KP& p, int gid) {
    if (gid < R_FUSE) {
        // fused W2U = msg_W2 @ upd_W1[128:256] and fbias; coalesced per 128-group
        int g = gid >> 7, n = gid & 127;
        int l = g / 129, kk = g % 129;
        const float* U1b = p.upd_W1 + (size_t)l * 32768 + 16384;
        if (kk < 128) {
            const float* w2row = p.msg_W2 + (size_t)l * 16384 + (size_t)kk * 128;
            float s = 0.f;
            for (int m = 0; m < 128; ++m) s += w2row[m] * U1b[m * 128 + n];
            p.wt[OFF_UPD1 + l * 32768 + n * 256 + 128 + kk] = (f16)s;
        } else {
            const float* b2 = p.msg_b2 + l * 128;
            float s = p.upd_b1[l * 128 + n];
            for (int m = 0; m < 128; ++m) s += b2[m] * U1b[m * 128 + n];
            p.fbias[l * 128 + n] = s;
        }
    } else if (gid < R_FUSE + R_WT) {
        int e = gid - R_FUSE;
        int j = 0;
#pragma unroll
        for (int i = 1; i < 20; ++i) j += (e >= p.wCum[i]) ? 1 : 0;
        int r = e - p.wCum[j];
        int K = p.wK[j];
        int k = r % K, n = r / K;
        p.wt[p.wOff[j] + n * p.wStr[j] + k] = (f16)p.wsrc[j][(size_t)k * 128 + n];
    } else if (gid < R_FUSE + R_WT + R_X) {
        int g2 = gid - (R_FUSE + R_WT);
        float4 v = ((const float4*)p.edge_features)[g2];
        f16x2 a = {(f16)v.x, (f16)v.y}, b = {(f16)v.z, (f16)v.w};
        ((f16x2*)p.xb)[g2 * 2] = a;
        ((f16x2*)p.xb)[g2 * 2 + 1] = b;
    } else if (gid < PTOT) {
        int z = gid - (R_FUSE + R_WT + R_X);
        p.segStart[z] = 0;
        p.segEnd[z] = 0;
    }
}

__device__ __forceinline__ void degseg_item(const KP& p, int i) {
    int d = p.adj_dst[i];
    if (i == 0 || p.adj_dst[i - 1] != d) p.segStart[d] = i;
    if (i == NA - 1 || p.adj_dst[i + 1] != d) p.segEnd[d] = i + 1;
}

// one 64-row tile: [agg into A-right]? -> GEMM1(K1) -> relu -> GEMM2 -> e' -> P/Q GEMMs
template <int K1, bool AGG>
__device__ __forceinline__ void do_tile(
    char* SMEM, int tile, const f16* __restrict__ in0,
    const f16* __restrict__ Pin, const f16* __restrict__ Qin,
    const int* __restrict__ adj_src, const int* __restrict__ segStart,
    const int* __restrict__ segEnd,
    const f16* __restrict__ w1t, const int w1s, const float* __restrict__ b1v,
    const f16* __restrict__ w2t, const float* __restrict__ b2v, const bool reluOut,
    f16* __restrict__ oute,
    const f16* __restrict__ wpq, const float* __restrict__ bPp,
    f16* __restrict__ Pout, f16* __restrict__ Qout) {
    constexpr int SA = K1 + 8;   // f16 stride
    constexpr int SH = 136;      // f16 stride for H/E
    f16* Abuf = (f16*)SMEM;
    f16* Hbuf = (f16*)SMEM;                  // aliases Abuf low (dead after GEMM1)
    f16* Ebuf = (f16*)(SMEM + 17408);        // after Hbuf; overlaps dead Abuf top
    const int t = threadIdx.x, lane = t & 63, wave = t >> 6;
    const int quad = lane >> 4, mn = lane & 15, n0 = wave * 32;
    const int rbase = tile << 6;

    // ---- stage A-tile (left half from global; right half from quad-gather agg)
    if constexpr (K1 == 64) {
#pragma unroll
        for (int it = 0; it < 2; ++it) {
            int u = it * 256 + t, row = u >> 3, k = (u & 7) * 8, gr = rbase + row;
            half8 v = {};
            if (gr < NE) v = *(const half8*)(in0 + (size_t)gr * 64 + k);
            *(half8*)(Abuf + row * SA + k) = v;
        }
    } else {
#pragma unroll
        for (int it = 0; it < 4; ++it) {
            int u = it * 256 + t, row = u >> 4, k = (u & 15) * 8, gr = rbase + row;
            half8 v = {};
            if (gr < NE) v = *(const half8*)(in0 + (size_t)gr * 128 + k);
            *(half8*)(Abuf + row * SA + k) = v;
        }
    }
    if constexpr (AGG) {
        // quartile-parallel gather: each quartile owns one dst per group;
        // lane reads half8 (16B) of Q[src] -> one instruction = 4 rows = 1KB in flight
        const int cl = mn;  // channel-lane 0..15, channels cl*8..cl*8+7
#pragma unroll
        for (int g = 0; g < 4; ++g) {
            int drow = wave * 16 + g * 4 + quad;
            int dst = rbase + drow;
            bool ok = dst < NE;
            int s = 0, deg = 0;
            if (ok) {
                s = segStart[dst];
                deg = segEnd[dst] - s;
            }
            bool iso = (deg == 0);
            int d1 = iso ? 1 : deg;
            half8 pv = {};
            if (ok) pv = *(const half8*)(Pin + (size_t)dst * 128 + cl * 8);
            float x[8] = {0.f, 0.f, 0.f, 0.f, 0.f, 0.f, 0.f, 0.f};
            if (ok) {
                int j = 0;
                for (; j + 3 < d1; j += 4) {
                    int s0 = adj_src[s + j];
                    int s1 = adj_src[s + j + 1];
                    int s2 = adj_src[s + j + 2];
                    int s3 = adj_src[s + j + 3];
                    half8 q0 = *(const half8*)(Qin + (size_t)s0 * 128 + cl * 8);
                    half8 q1 = *(const half8*)(Qin + (size_t)s1 * 128 + cl * 8);
                    half8 q2 = *(const half8*)(Qin + (size_t)s2 * 128 + cl * 8);
                    half8 q3 = *(const half8*)(Qin + (size_t)s3 * 128 + cl * 8);
#pragma unroll
                    for (int c2 = 0; c2 < 8; ++c2) {
                        float pc = (float)pv[c2];
                        x[c2] += fmaxf(pc + (float)q0[c2], 0.f) +
                                 fmaxf(pc + (float)q1[c2], 0.f) +
                                 fmaxf(pc + (float)q2[c2], 0.f) +
                                 fmaxf(pc + (float)q3[c2], 0.f);
                    }
                }
                for (; j < d1; ++j) {
                    int sj = iso ? dst : adj_src[s + j];
                    half8 qj = *(const half8*)(Qin + (size_t)sj * 128 + cl * 8);
#pragma unroll
                    for (int c2 = 0; c2 < 8; ++c2)
                        x[c2] += fmaxf((float)pv[c2] + (float)qj[c2], 0.f);
                }
                float sc = 1.f / (float)d1;
                half8 o;
#pragma unroll
                for (int c2 = 0; c2 < 8; ++c2) o[c2] = (f16)(x[c2] * sc);
                *(half8*)(Abuf + drow * SA + 128 + cl * 8) = o;
            }
        }
    }
    __syncthreads();

    // ---- GEMM1: [64 x K1] @ [K1 x 128] + b1, relu -> Hbuf
    f32x4 acc[4][2];
    {
        float bb0 = b1v[n0 + mn], bb1 = b1v[n0 + 16 + mn];
#pragma unroll
        for (int mt = 0; mt < 4; ++mt) {
            acc[mt][0] = (f32x4){bb0, bb0, bb0, bb0};
            acc[mt][1] = (f32x4){bb1, bb1, bb1, bb1};
        }
    }
#pragma unroll
    for (int kc = 0; kc < K1 / 32; ++kc) {
        half8 wA = *(const half8*)(w1t + (size_t)(n0 + mn) * w1s + kc * 32 + quad * 8);
        half8 wB = *(const half8*)(w1t + (size_t)(n0 + 16 + mn) * w1s + kc * 32 + quad * 8);
        half8 af[4];
#pragma unroll
        for (int mt = 0; mt < 4; ++mt)
            af[mt] = *(const half8*)(Abuf + (mt * 16 + mn) * SA + kc * 32 + quad * 8);
#pragma unroll
        for (int mt = 0; mt < 4; ++mt) {
            acc[mt][0] = __builtin_amdgcn_mfma_f32_16x16x32_f16(af[mt], wA, acc[mt][0], 0, 0, 0);
            acc[mt][1] = __builtin_amdgcn_mfma_f32_16x16x32_f16(af[mt], wB, acc[mt][1], 0, 0, 0);
        }
    }
    __syncthreads();  // A reads done before aliased Hbuf writes
#pragma unroll
    for (int mt = 0; mt < 4; ++mt)
#pragma unroll
        for (int nt = 0; nt < 2; ++nt)
#pragma unroll
            for (int r = 0; r < 4; ++r)
                Hbuf[(mt * 16 + quad * 4 + r) * SH + n0 + nt * 16 + mn] =
                    (f16)fmaxf(acc[mt][nt][r], 0.f);
    __syncthreads();

    // ---- GEMM2: [64x128]@[128x128] + b2 (+relu) -> Ebuf
    {
        float bb0 = b2v[n0 + mn], bb1 = b2v[n0 + 16 + mn];
#pragma unroll
        for (int mt = 0; mt < 4; ++mt) {
            acc[mt][0] = (f32x4){bb0, bb0, bb0, bb0};
            acc[mt][1] = (f32x4){bb1, bb1, bb1, bb1};
        }
    }
#pragma unroll
    for (int kc = 0; kc < 4; ++kc) {
        half8 wA = *(const half8*)(w2t + (size_t)(n0 + mn) * 128 + kc * 32 + quad * 8);
        half8 wB = *(const half8*)(w2t + (size_t)(n0 + 16 + mn) * 128 + kc * 32 + quad * 8);
        half8 af[4];
#pragma unroll
        for (int mt = 0; mt < 4; ++mt)
            af[mt] = *(const half8*)(Hbuf + (mt * 16 + mn) * SH + kc * 32 + quad * 8);
#pragma unroll
        for (int mt = 0; mt < 4; ++mt) {
            acc[mt][0] = __builtin_amdgcn_mfma_f32_16x16x32_f16(af[mt], wA, acc[mt][0], 0, 0, 0);
            acc[mt][1] = __builtin_amdgcn_mfma_f32_16x16x32_f16(af[mt], wB, acc[mt][1], 0, 0, 0);
        }
    }
#pragma unroll
    for (int mt = 0; mt < 4; ++mt)
#pragma unroll
        for (int nt = 0; nt < 2; ++nt)
#pragma unroll
            for (int r = 0; r < 4; ++r) {
                float v = acc[mt][nt][r];
                if (reluOut) v = fmaxf(v, 0.f);
                Ebuf[(mt * 16 + quad * 4 + r) * SH + n0 + nt * 16 + mn] = (f16)v;
            }
    __syncthreads();  // Ebuf ready

    // ---- vectorized e' store from Ebuf
#pragma unroll
    for (int it = 0; it < 4; ++it) {
        int u = it * 256 + t, row = u >> 4, k = (u & 15) * 8, gr = rbase + row;
        if (gr < NE) {
            half8 v = *(const half8*)(Ebuf + row * SH + k);
            *(half8*)(oute + (size_t)gr * 128 + k) = v;
        }
    }

    // ---- P GEMM (bias) then Q GEMM (no bias) on e'
    {
        float bb0 = bPp[n0 + mn], bb1 = bPp[n0 + 16 + mn];
#pragma unroll
        for (int mt = 0; mt < 4; ++mt) {
            acc[mt][0] = (f32x4){bb0, bb0, bb0, bb0};
            acc[mt][1] = (f32x4){bb1, bb1, bb1, bb1};
        }
    }
#pragma unroll
    for (int kc = 0; kc < 4; ++kc) {
        half8 wA = *(const half8*)(wpq + (size_t)(n0 + mn) * 128 + kc * 32 + quad * 8);
        half8 wB = *(const half8*)(wpq + (size_t)(n0 + 16 + mn) * 128 + kc * 32 + quad * 8);
        half8 af[4];
#pragma unroll
        for (int mt = 0; mt < 4; ++mt)
            af[mt] = *(const half8*)(Ebuf + (mt * 16 + mn) * SH + kc * 32 + quad * 8);
#pragma unroll
        for (int mt = 0; mt < 4; ++mt) {
            acc[mt][0] = __builtin_amdgcn_mfma_f32_16x16x32_f16(af[mt], wA, acc[mt][0], 0, 0, 0);
            acc[mt][1] = __builtin_amdgcn_mfma_f32_16x16x32_f16(af[mt], wB, acc[mt][1], 0, 0, 0);
        }
    }
#pragma unroll
    for (int mt = 0; mt < 4; ++mt)
#pragma unroll
        for (int nt = 0; nt < 2; ++nt)
#pragma unroll
            for (int r = 0; r < 4; ++r) {
                int gr = rbase + mt * 16 + quad * 4 + r;
                if (gr < NE)
                    Pout[(size_t)gr * 128 + n0 + nt * 16 + mn] = (f16)acc[mt][nt][r];
            }
#pragma unroll
    for (int mt = 0; mt < 4; ++mt) {
        acc[mt][0] = (f32x4){0.f, 0.f, 0.f, 0.f};
        acc[mt][1] = (f32x4){0.f, 0.f, 0.f, 0.f};
    }
#pragma unroll
    for (int kc = 0; kc < 4; ++kc) {
        half8 wA = *(const half8*)(wpq + 16384 + (size_t)(n0 + mn) * 128 + kc * 32 + quad * 8);
        half8 wB = *(const half8*)(wpq + 16384 + (size_t)(n0 + 16 + mn) * 128 + kc * 32 + quad * 8);
        half8 af[4];
#pragma unroll
        for (int mt = 0; mt < 4; ++mt)
            af[mt] = *(const half8*)(Ebuf + (mt * 16 + mn) * SH + kc * 32 + quad * 8);
#pragma unroll
        for (int mt = 0; mt < 4; ++mt) {
            acc[mt][0] = __builtin_amdgcn_mfma_f32_16x16x32_f16(af[mt], wA, acc[mt][0], 0, 0, 0);
            acc[mt][1] = __builtin_amdgcn_mfma_f32_16x16x32_f16(af[mt], wB, acc[mt][1], 0, 0, 0);
        }
    }
#pragma unroll
    for (int mt = 0; mt < 4; ++mt)
#pragma unroll
        for (int nt = 0; nt < 2; ++nt)
#pragma unroll
            for (int r = 0; r < 4; ++r) {
                int gr = rbase + mt * 16 + quad * 4 + r;
                if (gr < NE)
                    Qout[(size_t)gr * 128 + n0 + nt * 16 + mn] = (f16)acc[mt][nt][r];
            }
}

// one predictor tile: h1=relu(P1[i]+Q1[j]); h2=relu(h1@W2+b2); logit=h2@w3+b3; sigmoid
__device__ __forceinline__ void pred_tile(const KP& p, char* SMEM, float* w3s,
                                          float* psum, int tile, float b3v) {
    constexpr int SA = 136, SO = 133;
    f16* Abuf = (f16*)SMEM;
    float* Obuf = (float*)SMEM;
    const int t = threadIdx.x, lane = t & 63, wave = t >> 6;
    const int quad = lane >> 4, mn = lane & 15, n0 = wave * 32;
    const int rbase = tile << 6;
#pragma unroll
    for (int it = 0; it < 4; ++it) {
        int u = it * 256 + t, row = u >> 4, k = (u & 15) * 8, gr = rbase + row;
        half8 v = {};
        if (gr < NC) {
            int ii = p.cand_i[gr], jj = p.cand_j[gr];
            half8 a = *(const half8*)(p.P1 + (size_t)ii * 128 + k);
            half8 b = *(const half8*)(p.Q1 + (size_t)jj * 128 + k);
#pragma unroll
            for (int x = 0; x < 8; ++x)
                v[x] = (f16)fmaxf((float)a[x] + (float)b[x], 0.f);
        }
        *(half8*)(Abuf + row * SA + k) = v;
    }
    __syncthreads();
    f32x4 acc[4][2];
    {
        float bb0 = p.pred_b2[n0 + mn], bb1 = p.pred_b2[n0 + 16 + mn];
#pragma unroll
        for (int mt = 0; mt < 4; ++mt) {
            acc[mt][0] = (f32x4){bb0, bb0, bb0, bb0};
            acc[mt][1] = (f32x4){bb1, bb1, bb1, bb1};
        }
    }
#pragma unroll
    for (int kc = 0; kc < 4; ++kc) {
        half8 wA = *(const half8*)(p.wt + OFF_PREDW2 + (size_t)(n0 + mn) * 128 + kc * 32 + quad * 8);
        half8 wB = *(const half8*)(p.wt + OFF_PREDW2 + (size_t)(n0 + 16 + mn) * 128 + kc * 32 + quad * 8);
        half8 af[4];
#pragma unroll
        for (int mt = 0; mt < 4; ++mt)
            af[mt] = *(const half8*)(Abuf + (mt * 16 + mn) * SA + kc * 32 + quad * 8);
#pragma unroll
        for (int mt = 0; mt < 4; ++mt) {
            acc[mt][0] = __builtin_amdgcn_mfma_f32_16x16x32_f16(af[mt], wA, acc[mt][0], 0, 0, 0);
            acc[mt][1] = __builtin_amdgcn_mfma_f32_16x16x32_f16(af[mt], wB, acc[mt][1], 0, 0, 0);
        }
    }
    __syncthreads();  // Abuf reads done before aliased Obuf writes
#pragma unroll
    for (int mt = 0; mt < 4; ++mt)
#pragma unroll
        for (int nt = 0; nt < 2; ++nt)
#pragma unroll
            for (int r = 0; r < 4; ++r)
                Obuf[(mt * 16 + quad * 4 + r) * SO + n0 + nt * 16 + mn] =
                    fmaxf(acc[mt][nt][r], 0.f);
    __syncthreads();
    {
        int row = t & 63, q4 = t >> 6;
        float s = 0.f;
#pragma unroll
        for (int i = 0; i < 32; ++i)
            s += Obuf[row * SO + q4 * 32 + i] * w3s[q4 * 32 + i];
        psum[t] = s;
    }
    __syncthreads();
    if (t < 64) {
        int gr = rbase + t;
        if (gr < NC) {
            float lg = psum[t] + psum[t + 64] + psum[t + 128] + psum[t + 192] + b3v;
            p.outL[gr] = lg;
            p.outP[gr] = 1.f / (1.f + expf(-lg));
        }
    }
}

__device__ __forceinline__ void upd_layer_ptrs(const KP& p, int l,
    const f16*& ein, f16*& eout, const f16*& Pin, const f16*& Qin,
    f16*& Pout, f16*& Qout, const f16*& wpq, const float*& bP) {
    ein = (l & 1) ? p.eB : p.eA;
    eout = (l & 1) ? p.eA : p.eB;
    Pin = (l & 1) ? p.P1 : p.P0;
    Qin = (l & 1) ? p.Q1 : p.Q0;
    Pout = (l & 1) ? p.P0 : p.P1;
    Qout = (l & 1) ? p.Q0 : p.Q1;
    wpq = (l < 2) ? (p.wt + OFF_MSGPQ + (l + 1) * 32768) : (p.wt + OFF_PREDPQ);
    bP = (l < 2) ? (p.msg_b1 + (l + 1) * 128) : p.pred_b1;
}

// ---------------- plain launches ----------------
__global__ void k_prep(KP p) {
    int gid = blockIdx.x * 256 + threadIdx.x;
    if (gid < PTOT) prep_item(p, gid);
}
// encoder + PQ0 tile, then grid-stride degseg over NA
__global__ __launch_bounds__(256, 2) void k_encdeg(KP p) {
    __shared__ __align__(16) char SMEM[34816];
    do_tile<64, false>(SMEM, blockIdx.x, p.xb, nullptr, nullptr, nullptr, nullptr, nullptr,
                       p.wt + OFF_ENC1, 64, p.enc_b1, p.wt + OFF_ENC2, p.enc_b2, false,
                       p.eA, p.wt + OFF_MSGPQ, p.msg_b1, p.P0, p.Q0);
    const int nthr = gridDim.x * 256;
    for (int i = blockIdx.x * 256 + threadIdx.x; i < NA; i += nthr) degseg_item(p, i);
}
__global__ __launch_bounds__(256, 2) void k_upd(KP p, int l) {
    __shared__ __align__(16) char SMEM[34816];
    const f16 *ein, *Pin, *Qin, *wpq;
    f16 *eout, *Pout, *Qout;
    const float* bP;
    upd_layer_ptrs(p, l, ein, eout, Pin, Qin, Pout, Qout, wpq, bP);
    do_tile<256, true>(SMEM, blockIdx.x, ein, Pin, Qin, p.adj_src, p.segStart, p.segEnd,
                       p.wt + OFF_UPD1 + l * 32768, 256, p.fbias + l * 128,
                       p.wt + OFF_UPD2 + l * 16384, p.upd_b2 + l * 128, true,
                       eout, wpq, bP, Pout, Qout);
}
__global__ __launch_bounds__(256, 2) void k_pred(KP p) {
    __shared__ __align__(16) char SMEM[34816];
    __shared__ float w3s[128];
    __shared__ float psum[256];
    if (threadIdx.x < 128) w3s[threadIdx.x] = p.pred_W3[threadIdx.x];
    float b3v = p.pred_b3[0];
    pred_tile(p, SMEM, w3s, psum, blockIdx.x, b3v);
}

// ---------------- host ----------------
extern "C" void kernel_launch(void* const* d_in, const int* in_sizes, int n_in,
                              void* d_out, int out_size, void* d_ws, size_t ws_size,
                              hipStream_t stream) {
    KP p;
    p.edge_features = (const float*)d_in[0];
    p.adj_dst = (const int*)d_in[1];
    p.adj_src = (const int*)d_in[2];
    p.cand_i = (const int*)d_in[3];
    p.cand_j = (const int*)d_in[4];
    const float* enc_W1 = (const float*)d_in[5];
    p.enc_b1 = (const float*)d_in[6];
    const float* enc_W2 = (const float*)d_in[7];
    p.enc_b2 = (const float*)d_in[8];
    const float* msg_W1 = (const float*)d_in[9];
    p.msg_b1 = (const float*)d_in[10];
    p.msg_W2 = (const float*)d_in[11];
    p.msg_b2 = (const float*)d_in[12];
    p.upd_W1 = (const float*)d_in[13];
    p.upd_b1 = (const float*)d_in[14];
    const float* upd_W2 = (const float*)d_in[15];
    p.upd_b2 = (const float*)d_in[16];
    const float* pred_W1 = (const float*)d_in[17];
    p.pred_b1 = (const float*)d_in[18];
    const float* pred_W2 = (const float*)d_in[19];
    p.pred_b2 = (const float*)d_in[20];
    p.pred_W3 = (const float*)d_in[21];
    p.pred_b3 = (const float*)d_in[22];

    char* ws = (char*)d_ws;
    size_t off = 0;
    auto alloc = [&](size_t bytes) -> void* {
        void* q = ws + off;
        off = (off + bytes + 255) & ~(size_t)255;
        return q;
    };
    p.wt = (f16*)alloc((size_t)TOTAL_WT * 2);
    p.fbias = (float*)alloc(3 * 128 * 4);
    p.xb = (f16*)alloc((size_t)NE * 64 * 2);
    p.eA = (f16*)alloc((size_t)NE * 128 * 2);
    p.eB = (f16*)alloc((size_t)NE * 128 * 2);
    p.P0 = (f16*)alloc((size_t)NE * 128 * 2);
    p.Q0 = (f16*)alloc((size_t)NE * 128 * 2);
    p.P1 = (f16*)alloc((size_t)NE * 128 * 2);
    p.Q1 = (f16*)alloc((size_t)NE * 128 * 2);
    p.segStart = (int*)alloc((size_t)NE * 4);
    p.segEnd = (int*)alloc((size_t)NE * 4);
    p.outP = (float*)d_out;
    p.outL = (float*)d_out + NC;

    int idx = 0, c = 0;
    auto addj = [&](const float* s, int K, int o, int st) {
        p.wsrc[idx] = s; p.wK[idx] = K; p.wOff[idx] = o;
        p.wStr[idx] = st; p.wCum[idx] = c;
        c += K * 128; idx++;
    };
    addj(enc_W1, 64, OFF_ENC1, 64);
    addj(enc_W2, 128, OFF_ENC2, 128);
    for (int l = 0; l < 3; ++l) addj(msg_W1 + (size_t)l * 32768, 128, OFF_MSGPQ + l * 32768, 128);
    for (int l = 0; l < 3; ++l) addj(msg_W1 + (size_t)l * 32768 + 16384, 128, OFF_MSGPQ + l * 32768 + 16384, 128);
    for (int l = 0; l < 3; ++l) addj(p.upd_W1 + (size_t)l * 32768, 128, OFF_UPD1 + l * 32768, 256);
    for (int l = 0; l < 3; ++l) addj(upd_W2 + (size_t)l * 16384, 128, OFF_UPD2 + l * 16384, 128);
    addj(pred_W1, 128, OFF_PREDPQ, 128);
    addj(pred_W1 + 16384, 128, OFF_PREDPQ + 16384, 128);
    addj(pred_W2, 128, OFF_PREDW2, 128);
    for (int i = idx; i <= 20; ++i) p.wCum[i] = c;  // c == 270336 == R_WT

    const int tilesNE = (NE + 63) / 64;   // 782
    const int tilesNC = (NC + 63) / 64;   // 1563
    k_prep<<<(PTOT + 255) / 256, 256, 0, stream>>>(p);
    k_encdeg<<<tilesNE, 256, 0, stream>>>(p);
    for (int l = 0; l < 3; ++l) k_upd<<<tilesNE, 256, 0, stream>>>(p, l);
    k_pred<<<tilesNC, 256, 0, stream>>>(p);

    (void)in_sizes; (void)n_in; (void)out_size; (void)ws_size;
}